// Round 5
// baseline (194.730 us; speedup 1.0000x reference)
//
#include <hip/hip_runtime.h>

// GAE reverse scan: adv[t] = delta[t] + (gamma*lambda)*adv[t+1]
// delta[t] = reward[t] + gamma*value[t+1] - value[t]
//
// Recompute-structured 3-pass chunked linear recurrence (exact):
//   K1 gae_sum   : per-(chunk, col4) local suffix sum -> S only (8 MB).
//   K2 gae_carry : per-scalar-column reverse scan over chunk sums, in place:
//                  S[c] <- carry entering chunk c.
//   K3 gae_emit  : re-read inputs (L3-resident after K1: 131 MB inputs + small
//                  writes < 256 MB Infinity Cache), scan with true carry,
//                  write out ONCE.  Avoids R4's triple `out` traffic.
// All loads batched into registers before compute; __launch_bounds__(256,4)
// gives the scheduler a 128-VGPR budget so the batches stay hoisted
// (R4 post-mortem: default occupancy targeting sank them, VGPR=36).

constexpr int T_ = 1024;
constexpr int B_ = 16384;
constexpr float GAMMA = 0.99f;
constexpr float COEF  = (float)(0.99 * 0.97);

__host__ __device__ constexpr float pow_coef(int n) {
    float p = 1.0f;
    for (int i = 0; i < n; ++i) p *= COEF;
    return p;
}

// ---------------- K1: batched local chunk sums ----------------
template <int L>
__global__ __launch_bounds__(256, 4) void gae_sum(
    const float* __restrict__ value,   // (T+1, B)
    const float* __restrict__ reward,  // (T, B)
    float* __restrict__ S)             // (T/L, B)
{
    const int c4    = blockIdx.x * 256 + threadIdx.x;
    const int chunk = blockIdx.y;
    const size_t b  = (size_t)c4 * 4;
    const int t0    = chunk * L;

    float4 v[L + 1];
    float4 r[L];
    #pragma unroll
    for (int i = 0; i <= L; ++i)
        v[i] = *(const float4*)(value + (size_t)(t0 + i) * B_ + b);
    #pragma unroll
    for (int i = 0; i < L; ++i)
        r[i] = *(const float4*)(reward + (size_t)(t0 + i) * B_ + b);

    float4 s = make_float4(0.f, 0.f, 0.f, 0.f);
    #pragma unroll
    for (int i = L - 1; i >= 0; --i) {
        s.x = (r[i].x + GAMMA * v[i + 1].x - v[i].x) + COEF * s.x;
        s.y = (r[i].y + GAMMA * v[i + 1].y - v[i].y) + COEF * s.y;
        s.z = (r[i].z + GAMMA * v[i + 1].z - v[i].z) + COEF * s.z;
        s.w = (r[i].w + GAMMA * v[i + 1].w - v[i].w) + COEF * s.w;
    }
    *(float4*)(S + (size_t)chunk * B_ + b) = s;
}

// ---------------- K2: in-place carry scan, one thread per scalar column ----
template <int L>
__global__ __launch_bounds__(256, 1) void gae_carry(float* __restrict__ S)
{
    constexpr int C  = T_ / L;
    constexpr float CL = pow_coef(L);
    const int col = blockIdx.x * 256 + threadIdx.x;   // 0..B-1

    float s[C];
    #pragma unroll
    for (int j = 0; j < C; ++j)
        s[j] = S[(size_t)j * B_ + col];               // batched loads

    float run = 0.f;
    #pragma unroll
    for (int j = C - 1; j >= 0; --j) {
        S[(size_t)j * B_ + col] = run;                // carry entering chunk j
        run = s[j] + CL * run;
    }
}

// ---------------- K3: recompute scan with true carry, emit out ----------------
template <int L>
__global__ __launch_bounds__(256, 4) void gae_emit(
    const float* __restrict__ value,
    const float* __restrict__ reward,
    const float* __restrict__ S,       // carries
    float* __restrict__ out)           // (T, B)
{
    const int c4    = blockIdx.x * 256 + threadIdx.x;
    const int chunk = blockIdx.y;
    const size_t b  = (size_t)c4 * 4;
    const int t0    = chunk * L;

    float4 carry = *(const float4*)(S + (size_t)chunk * B_ + b);

    float4 v[L + 1];
    float4 r[L];
    #pragma unroll
    for (int i = 0; i <= L; ++i)
        v[i] = *(const float4*)(value + (size_t)(t0 + i) * B_ + b);
    #pragma unroll
    for (int i = 0; i < L; ++i)
        r[i] = *(const float4*)(reward + (size_t)(t0 + i) * B_ + b);

    float4 a = carry;
    #pragma unroll
    for (int i = L - 1; i >= 0; --i) {
        a.x = (r[i].x + GAMMA * v[i + 1].x - v[i].x) + COEF * a.x;
        a.y = (r[i].y + GAMMA * v[i + 1].y - v[i].y) + COEF * a.y;
        a.z = (r[i].z + GAMMA * v[i + 1].z - v[i].z) + COEF * a.z;
        a.w = (r[i].w + GAMMA * v[i + 1].w - v[i].w) + COEF * a.w;
        *(float4*)(out + (size_t)(t0 + i) * B_ + b) = a;
    }
}

template <int L>
static void launch_all(const float* value, const float* reward,
                       float* S, float* out, hipStream_t stream) {
    constexpr int C = T_ / L;
    dim3 block(256);
    dim3 gridA(B_ / 4 / 256, C);
    dim3 gridC(B_ / 256);
    gae_sum<L>  <<<gridA, block, 0, stream>>>(value, reward, S);
    gae_carry<L><<<gridC, block, 0, stream>>>(S);
    gae_emit<L> <<<gridA, block, 0, stream>>>(value, reward, S, out);
}

extern "C" void kernel_launch(void* const* d_in, const int* in_sizes, int n_in,
                              void* d_out, int out_size, void* d_ws, size_t ws_size,
                              hipStream_t stream) {
    const float* value  = (const float*)d_in[0];   // (T+1, B)
    const float* reward = (const float*)d_in[1];   // (T, B)
    float* out = (float*)d_out;
    float* S   = (float*)d_ws;

    if (ws_size >= (size_t)(T_ / 8) * B_ * 4) {
        launch_all<8>(value, reward, S, out, stream);    // C=128: 8 MB ws
    } else {
        launch_all<16>(value, reward, S, out, stream);   // C=64: 4 MB ws
    }
}